// Round 11
// baseline (516.127 us; speedup 1.0000x reference)
//
#include <hip/hip_runtime.h>

typedef __attribute__((ext_vector_type(8))) _Float16 halfx8;
typedef __attribute__((ext_vector_type(4))) float f32x4;

#define MFMA16H(a, b, c) __builtin_amdgcn_mfma_f32_16x16x32_f16(a, b, c, 0, 0, 0)

#define T_SEQ 512
#define F_IN 32
#define H1 128
#define E2 64
#define ROWS 4          // batch rows per block

__device__ __forceinline__ ushort f2h(float f) {
    _Float16 h = (_Float16)f;              // v_cvt_f16_f32, RNE
    return __builtin_bit_cast(ushort, h);
}
__device__ __forceinline__ float fast_sigmoid(float x) {
    float e = __expf(-x);
    return __builtin_amdgcn_rcpf(1.0f + e);
}
__device__ __forceinline__ float fast_tanh(float x) {
    float e = __expf(-2.0f * x);
    return 2.0f * __builtin_amdgcn_rcpf(1.0f + e) - 1.0f;
}
__device__ __forceinline__ halfx8 load_w8h(const float* p) {
    halfx8 r;
#pragma unroll
    for (int j = 0; j < 8; ++j) r[j] = (_Float16)p[j];
    return r;
}

// Fused 2-layer LSTM, 128 blocks x 512 threads (8 waves), 4 batch rows/blk.
//
// ROUND THEORY (hoist x-GEMM out of the recurrence; r10 retry, compile fix):
// r8/r9 step = ~2100cyc, pipe floor 64 MFMA/SIMD x 20.6 = 1320. The L1
// x-contribution (8 MFMA/wave/step) doesn't depend on h: it was being
// recomputed in the serial loop with 4x-redundant M. Here L2 waves (24 vs 40
// MFMA -> slack) compute xg = bias + x@Wih1^T for t-block tt/4+1 in an
// 8-MFMA burst every 4th step, M-PACKED (16 distinct (t,r) rows/MFMA -> 4x
// denser) into a fp32 LDS ring. L1: acc=0, 32 h-MFMAs, epilogue adds xg.
// Per-SIMD MFMA 64->58; L1 stream 40->32.
//  - xg ring: flat strides slot=2088, r=520 dwords (== 8 mod 32): both the
//    L2 scatter-write (quad spread via slot) and L1 b128 read (quad spread
//    via r) are 2-way bank = free.
//  - xa (x A-tiles, rt=(t&3)*4+r rows): MFMA C row quad*4+j -> (sub-t=quad,
//    batch row=j): each lane writes 4 j-rows of one (t,u) pair per nt.
//  - static indexing everywhere (rule #20): xg burst unrolls nt 0..7.
// Gate k-order per output unchanged (bias+x group, then h kt0..3); one final
// fp32 re-association (~ulp). L2 layer math identical to r8.
__global__ __launch_bounds__(512, 1) void lstm_fused(
    const float* __restrict__ x,      // [512][512][32]
    const float* __restrict__ Wih1,   // [512][32]
    const float* __restrict__ Whh1,   // [512][128]
    const float* __restrict__ bih1,   // [512]
    const float* __restrict__ bhh1,   // [512]
    const float* __restrict__ Wih2,   // [256][128]
    const float* __restrict__ Whh2,   // [256][64]
    const float* __restrict__ bih2,   // [256]
    const float* __restrict__ bhh2,   // [256]
    float* __restrict__ out)          // [512][64] fp32
{
    __shared__ __align__(16) ushort xa [4][16][40];   // fp16 x A-tiles, rt x 32
    __shared__ __align__(16) float  xgl[8 * 2088];    // xg ring: [slot][r][u][g] swizzle-padded
    __shared__ __align__(16) ushort h1s[2][ROWS][144];// fp16 h1, cols 0..127
    __shared__ __align__(16) ushort h2s[2][ROWS][80]; // fp16 h2, cols 0..63
#define XGI(s, r, u) ((s) * 2088 + (r) * 520 + (u) * 4)

    const int tid  = threadIdx.x;
    const int wave = tid >> 6;
    const int lane = tid & 63;
    const int l15  = lane & 15;
    const int quad = lane >> 4;
    const int arow = l15 >> 2;        // broadcast A-row (batch row) for h reads
    const int r0   = blockIdx.x * ROWS;
    const bool isL1 = (wave < 4);
    const int w    = wave & 3;

    // Weight fragment file (disjoint per wave group), fp16:
    //  L1: wf[tau*4+kt] = Whh1 frag (tau = g*2+uo), 32 frags. No bias needed.
    //  L2: wf[g*4+kt] = Wih2, wf[16+g*2+kc] = Whh2, wf[24+tau] = Wih1 (xg job)
    halfx8 wf[32];
    float  bias2[4], bx[8];

    if (isL1) {
#pragma unroll
        for (int g = 0; g < 4; ++g)
#pragma unroll
            for (int uo = 0; uo < 2; ++uo) {
                const int tau = g * 2 + uo;
                const int n = g * 128 + w * 32 + uo * 16 + l15;
#pragma unroll
                for (int kt = 0; kt < 4; ++kt)
                    wf[tau * 4 + kt] = load_w8h(Whh1 + n * H1 + kt * 32 + quad * 8);
            }
    } else {
#pragma unroll
        for (int g = 0; g < 4; ++g) {
            const int n2 = g * 64 + w * 16 + l15;
#pragma unroll
            for (int kt = 0; kt < 4; ++kt)
                wf[g * 4 + kt] = load_w8h(Wih2 + n2 * H1 + kt * 32 + quad * 8);
#pragma unroll
            for (int kc = 0; kc < 2; ++kc)
                wf[16 + g * 2 + kc] = load_w8h(Whh2 + n2 * E2 + kc * 32 + quad * 8);
            bias2[g] = bih2[n2] + bhh2[n2];
        }
#pragma unroll
        for (int g = 0; g < 4; ++g)
#pragma unroll
            for (int uo = 0; uo < 2; ++uo) {
                const int tau = g * 2 + uo;
                const int n = g * 128 + w * 32 + uo * 16 + l15;
                wf[24 + tau] = load_w8h(Wih1 + n * F_IN + quad * 8);
                bx[tau] = bih1[n] + bhh1[n];
            }
    }

    // zero both h-state buffers
    for (int i = tid; i < 2 * ROWS * 144; i += 512) ((ushort*)h1s)[i] = 0;
    for (int i = tid; i < 2 * ROWS * 80;  i += 512) ((ushort*)h2s)[i] = 0;

    // cell states: lane (quad,l15) owns batch row 'quad'
    float cst[2] = {0.0f, 0.0f};      // L1: per uo; L2 uses cst[0]

    // x staging into xa (rt layout): 32 lanes of each L2 wave; wave 4+w -> row w
    const bool stager = (!isL1) && (lane < 32);
    const float* xptr = x + ((size_t)(r0 + w) * T_SEQ) * F_IN + lane;
    float xr8[8];
#pragma unroll
    for (int j = 0; j < 8; ++j) xr8[j] = 0.0f;
    if (stager) {
        float t0[8];
#pragma unroll
        for (int j = 0; j < 8; ++j) t0[j] = xptr[(size_t)j * F_IN];
#pragma unroll
        for (int j = 0; j < 8; ++j)
            xa[(j >> 2) & 3][(j & 3) * 4 + w][lane] = f2h(t0[j]);
#pragma unroll
        for (int j = 0; j < 8; ++j) xr8[j] = xptr[(size_t)(8 + j) * F_IN];
    }
    __syncthreads();

    // prologue: L2 waves compute xg for t-block 0 (t = 0..3)
    if (!isL1) {
        const halfx8 af = *(const halfx8*)&xa[0][l15][quad * 8];
#pragma unroll
        for (int nt = 0; nt < 8; ++nt) {
            const float b = bx[nt];
            const f32x4 cinit = {b, b, b, b};
            const f32x4 d = MFMA16H(af, wf[24 + nt], cinit);
            const int uu = w * 32 + (nt & 1) * 16 + l15;
#pragma unroll
            for (int j = 0; j < 4; ++j)
                xgl[XGI(quad, j, uu) + (nt >> 1)] = d[j];   // slot = (0*4+quad)&7
        }
    }
    __syncthreads();

#pragma unroll 1
    for (int tt = 0; tt <= T_SEQ; ++tt) {
        const int p  = tt & 1;
        const int pn = p ^ 1;

        if (isL1) {
            if (tt < T_SEQ) {
                // xg loads: issued early, hidden under the MFMA stream
                const f32x4 xg0 = *(const f32x4*)&xgl[XGI(tt & 7, quad, w * 32 + l15)];
                const f32x4 xg1 = *(const f32x4*)&xgl[XGI(tt & 7, quad, w * 32 + 16 + l15)];
                halfx8 hf[4];
#pragma unroll
                for (int kt = 0; kt < 4; ++kt)
                    hf[kt] = *(const halfx8*)&h1s[p][arow][kt * 32 + quad * 8];
                // ---- L1 GEMM: 8 taus x 4 h-ktiles, acc from zero ----
                f32x4 acc[8];
#pragma unroll
                for (int tau = 0; tau < 8; ++tau)
                    acc[tau] = (f32x4){0.0f, 0.0f, 0.0f, 0.0f};
                __builtin_amdgcn_s_setprio(1);
#pragma unroll
                for (int kt = 0; kt < 4; ++kt)
#pragma unroll
                    for (int tau = 0; tau < 8; ++tau)
                        acc[tau] = MFMA16H(hf[kt], wf[tau * 4 + kt], acc[tau]);
                __builtin_amdgcn_s_setprio(0);
                // ---- L1 epilogue: h-sum + xg (bias + x contribution) ----
#pragma unroll
                for (int uo = 0; uo < 2; ++uo) {
                    const f32x4 xgv = uo ? xg1 : xg0;
                    const int u = w * 32 + uo * 16 + l15;
                    const float iv = fast_sigmoid(acc[0 + uo][0] + xgv[0]);
                    const float fv = fast_sigmoid(acc[2 + uo][0] + xgv[1]);
                    const float gv = fast_tanh   (acc[4 + uo][0] + xgv[2]);
                    const float ov = fast_sigmoid(acc[6 + uo][0] + xgv[3]);
                    const float cn = fv * cst[uo] + iv * gv;
                    cst[uo] = cn;
                    const float h = ov * fast_tanh(cn);
                    h1s[pn][quad][u] = f2h(h);
                }
            }
        } else {
            if (tt >= 1) {
                // ---- L2 GEMM: 4 gates x 16 units, K = 128(h1) + 64(h2) ----
                f32x4 acc2[4];
#pragma unroll
                for (int g = 0; g < 4; ++g)
                    acc2[g] = (f32x4){bias2[g], bias2[g], bias2[g], bias2[g]};
                __builtin_amdgcn_s_setprio(1);
#pragma unroll
                for (int kt = 0; kt < 4; ++kt) {
                    const halfx8 a = *(const halfx8*)&h1s[p][arow][kt * 32 + quad * 8];
#pragma unroll
                    for (int g = 0; g < 4; ++g)
                        acc2[g] = MFMA16H(a, wf[g * 4 + kt], acc2[g]);
                }
#pragma unroll
                for (int kc = 0; kc < 2; ++kc) {
                    const halfx8 a = *(const halfx8*)&h2s[p][arow][kc * 32 + quad * 8];
#pragma unroll
                    for (int g = 0; g < 4; ++g)
                        acc2[g] = MFMA16H(a, wf[16 + g * 2 + kc], acc2[g]);
                }
                __builtin_amdgcn_s_setprio(0);
                // ---- L2 epilogue ----
                const int u = w * 16 + l15;
                const float iv = fast_sigmoid(acc2[0][0]);
                const float fv = fast_sigmoid(acc2[1][0]);
                const float gv = fast_tanh   (acc2[2][0]);
                const float ov = fast_sigmoid(acc2[3][0]);
                const float cn = fv * cst[0] + iv * gv;
                cst[0] = cn;
                const float h = ov * fast_tanh(cn);
                if (tt == T_SEQ) {
                    out[(size_t)(r0 + quad) * E2 + u] = h;
                } else {
                    h2s[pn][quad][u] = f2h(h);
                }
            }
            // ---- xg burst: every 4th step, compute t-block tt/4 + 1 ----
            if ((tt & 3) == 0) {
                const int tb = (tt >> 2) + 1;
                if (tb < (T_SEQ >> 2)) {
                    const halfx8 af = *(const halfx8*)&xa[tb & 3][l15][quad * 8];
#pragma unroll
                    for (int nt = 0; nt < 8; ++nt) {
                        const float b = bx[nt];
                        const f32x4 cinit = {b, b, b, b};
                        const f32x4 d = MFMA16H(af, wf[24 + nt], cinit);
                        const int uu = w * 32 + (nt & 1) * 16 + l15;
                        const int slot = (tb * 4 + quad) & 7;
#pragma unroll
                        for (int j = 0; j < 4; ++j)
                            xgl[XGI(slot, j, uu) + (nt >> 1)] = d[j];
                    }
                }
            }
            // ---- batched xa staging, once every 8 steps ----
            if (stager && (tt & 7) == 0) {
#pragma unroll
                for (int j = 0; j < 8; ++j) {
                    const int t = tt + 8 + j;
                    if (t < T_SEQ)
                        xa[(t >> 2) & 3][(t & 3) * 4 + w][lane] = f2h(xr8[j]);
                }
#pragma unroll
                for (int j = 0; j < 8; ++j) {
                    const int t = tt + 16 + j;
                    if (t < T_SEQ) xr8[j] = xptr[(size_t)t * F_IN];
                }
            }
        }
        __syncthreads();   // single barrier per step
    }
#undef XGI
}

extern "C" void kernel_launch(void* const* d_in, const int* in_sizes, int n_in,
                              void* d_out, int out_size, void* d_ws, size_t ws_size,
                              hipStream_t stream) {
    lstm_fused<<<128, 512, 0, stream>>>(
        (const float*)d_in[0], (const float*)d_in[1], (const float*)d_in[2],
        (const float*)d_in[3], (const float*)d_in[4], (const float*)d_in[5],
        (const float*)d_in[6], (const float*)d_in[7], (const float*)d_in[8],
        (float*)d_out);
}

// Round 12
// 483.348 us; speedup vs baseline: 1.0678x; 1.0678x over previous
//
#include <hip/hip_runtime.h>

typedef __attribute__((ext_vector_type(8))) _Float16 halfx8;
typedef __attribute__((ext_vector_type(4))) float f32x4;

#define MFMA16H(a, b, c) __builtin_amdgcn_mfma_f32_16x16x32_f16(a, b, c, 0, 0, 0)

#define T_SEQ 512
#define F_IN 32
#define H1 128
#define E2 64
#define ROWS 4          // batch rows per block

__device__ __forceinline__ ushort f2h(float f) {
    _Float16 h = (_Float16)f;              // v_cvt_f16_f32, RNE
    return __builtin_bit_cast(ushort, h);
}
__device__ __forceinline__ float fast_sigmoid(float x) {
    float e = __expf(-x);
    return __builtin_amdgcn_rcpf(1.0f + e);
}
__device__ __forceinline__ float fast_tanh(float x) {
    float e = __expf(-2.0f * x);
    return 2.0f * __builtin_amdgcn_rcpf(1.0f + e) - 1.0f;
}
__device__ __forceinline__ halfx8 load_w8h(const float* p) {
    halfx8 r;
#pragma unroll
    for (int j = 0; j < 8; ++j) r[j] = (_Float16)p[j];
    return r;
}

// Fused 2-layer LSTM, 128 blocks x 768 threads (12 waves), 4 batch rows/blk.
//
// ROUND THEORY (3rd wave per SIMD as independent issuer): r8's 2020cyc step
// = ~1050 MFMA-pipe busy + ~970 lockstep serial chain (ds-head ~120,
// epilogue ~180, fill losses, barrier skew) during which ALL waves stall
// together (2/SIMD, same phases). r11's xg-hoist regressed (bursty
// asymmetric work inside a barrier interval); r6/r9 scheduling nulls. This
// round: 12 waves, SAME total 64 MFMA/SIMD, but 3 independent streams:
//  - L1 split 8 ways: wave w owns 4 gates x units [16w,16w+16):
//    16 Whh1 + 4 Wih1 frags = 80 regs, 20 MFMA, 1 epilogue update/lane.
//  - L2 split 4 ways (waves 8-11): identical to r8 (96 regs, 24 MFMA).
//  - per SIMD: 2 L1 + 1 L2; when one wave is in its ds-head/epilogue the
//    other two keep the matrix pipe fed; per-wave tails shrink (20/24 vs 40).
// Demand: L1 ~115, L2 ~135 vs ~170 cap at 3 waves/SIMD -> spill none-to-
// benign (r0-class), far from r5's thrash regime.
// Per-output accumulate order identical to r8 -> bit-identical numerics.
__global__ __launch_bounds__(768, 1) void lstm_fused(
    const float* __restrict__ x,      // [512][512][32]
    const float* __restrict__ Wih1,   // [512][32]
    const float* __restrict__ Whh1,   // [512][128]
    const float* __restrict__ bih1,   // [512]
    const float* __restrict__ bhh1,   // [512]
    const float* __restrict__ Wih2,   // [256][128]
    const float* __restrict__ Whh2,   // [256][64]
    const float* __restrict__ bih2,   // [256]
    const float* __restrict__ bhh2,   // [256]
    float* __restrict__ out)          // [512][64] fp32
{
    __shared__ __align__(16) ushort xs [16][ROWS][80];  // fp16 x(t) ring, cols 0..31
    __shared__ __align__(16) ushort h1s[2][ROWS][144];  // fp16 h1, cols 0..127
    __shared__ __align__(16) ushort h2s[2][ROWS][80];   // fp16 h2, cols 0..63

    const int tid  = threadIdx.x;
    const int wave = tid >> 6;
    const int lane = tid & 63;
    const int l15  = lane & 15;
    const int quad = lane >> 4;
    const int arow = l15 >> 2;        // broadcast A-row (batch row) for ds_reads
    const int r0   = blockIdx.x * ROWS;
    const bool isL1 = (wave < 8);

    // Weight fragment file (disjoint per wave group), fp16:
    //  L1 (wave 0..7):  wf[g*4+kt] = Whh1 frag (16), wf[16+g] = Wih1 (4)
    //  L2 (wave 8..11): wf[g*4+kt] = Wih2 (16), wf[16+g*2+kc] = Whh2 (8)
    halfx8 wf[24];
    float  bias[4];

    if (isL1) {
#pragma unroll
        for (int g = 0; g < 4; ++g) {
            const int n = g * 128 + wave * 16 + l15;
#pragma unroll
            for (int kt = 0; kt < 4; ++kt)
                wf[g * 4 + kt] = load_w8h(Whh1 + n * H1 + kt * 32 + quad * 8);
            wf[16 + g] = load_w8h(Wih1 + n * F_IN + quad * 8);
            bias[g] = bih1[n] + bhh1[n];
        }
    } else {
        const int w2 = wave - 8;
#pragma unroll
        for (int g = 0; g < 4; ++g) {
            const int n = g * 64 + w2 * 16 + l15;
#pragma unroll
            for (int kt = 0; kt < 4; ++kt)
                wf[g * 4 + kt] = load_w8h(Wih2 + n * H1 + kt * 32 + quad * 8);
#pragma unroll
            for (int kc = 0; kc < 2; ++kc)
                wf[16 + g * 2 + kc] = load_w8h(Whh2 + n * E2 + kc * 32 + quad * 8);
            bias[g] = bih2[n] + bhh2[n];
        }
    }

    // zero both h-state buffers (fp16 zero == 0 bits)
    for (int i = tid; i < 2 * ROWS * 144; i += 768) ((ushort*)h1s)[i] = 0;
    for (int i = tid; i < 2 * ROWS * 80;  i += 768) ((ushort*)h2s)[i] = 0;

    // cell state: lane (quad,l15) owns batch row 'quad'; one unit per lane
    float cst = 0.0f;

    // x staging: 32 lanes of each L2 wave; wave 8+xr stages batch row xr.
    const int w2s  = wave & 3;        // for L2 waves: batch row to stage
    const bool stager = (!isL1) && (lane < 32);
    const float* xptr = x + ((size_t)(r0 + w2s) * T_SEQ) * F_IN + lane;
    float xr8[8];
#pragma unroll
    for (int j = 0; j < 8; ++j) xr8[j] = 0.0f;
    if (stager) {
        // prologue: stage t=0..7 into slots 0..7, prefetch t=8..15 into regs
        float t0[8];
#pragma unroll
        for (int j = 0; j < 8; ++j) t0[j] = xptr[(size_t)j * F_IN];
#pragma unroll
        for (int j = 0; j < 8; ++j) xs[j][w2s][lane] = f2h(t0[j]);
#pragma unroll
        for (int j = 0; j < 8; ++j) xr8[j] = xptr[(size_t)(8 + j) * F_IN];
    }
    __syncthreads();

#pragma unroll 1
    for (int tt = 0; tt <= T_SEQ; ++tt) {
        const int p  = tt & 1;
        const int pn = p ^ 1;

        if (isL1) {
            if (tt < T_SEQ) {
                // ---- L1 GEMM: 4 gates x 16 units, K = 32(x) + 128(h1) ----
                f32x4 acc[4];
#pragma unroll
                for (int g = 0; g < 4; ++g)
                    acc[g] = (f32x4){bias[g], bias[g], bias[g], bias[g]};
                const halfx8 ax = *(const halfx8*)&xs[tt & 15][arow][quad * 8];
                halfx8 hf[4];
#pragma unroll
                for (int kt = 0; kt < 4; ++kt)
                    hf[kt] = *(const halfx8*)&h1s[p][arow][kt * 32 + quad * 8];
                __builtin_amdgcn_s_setprio(1);
#pragma unroll
                for (int g = 0; g < 4; ++g)
                    acc[g] = MFMA16H(ax, wf[16 + g], acc[g]);
#pragma unroll
                for (int kt = 0; kt < 4; ++kt)
#pragma unroll
                    for (int g = 0; g < 4; ++g)
                        acc[g] = MFMA16H(hf[kt], wf[g * 4 + kt], acc[g]);
                __builtin_amdgcn_s_setprio(0);
                // ---- L1 epilogue, in-register: 1 update per lane ----
                const int u = wave * 16 + l15;
                const float iv = fast_sigmoid(acc[0][0]);
                const float fv = fast_sigmoid(acc[1][0]);
                const float gv = fast_tanh   (acc[2][0]);
                const float ov = fast_sigmoid(acc[3][0]);
                const float cn = fv * cst + iv * gv;
                cst = cn;
                const float h = ov * fast_tanh(cn);
                h1s[pn][quad][u] = f2h(h);
            }
        } else {
            if (tt >= 1) {
                // ---- L2 GEMM: 4 gates x 16 units, K = 128(h1) + 64(h2) ----
                f32x4 acc2[4];
#pragma unroll
                for (int g = 0; g < 4; ++g)
                    acc2[g] = (f32x4){bias[g], bias[g], bias[g], bias[g]};
                __builtin_amdgcn_s_setprio(1);
#pragma unroll
                for (int kt = 0; kt < 4; ++kt) {
                    const halfx8 a = *(const halfx8*)&h1s[p][arow][kt * 32 + quad * 8];
#pragma unroll
                    for (int g = 0; g < 4; ++g)
                        acc2[g] = MFMA16H(a, wf[g * 4 + kt], acc2[g]);
                }
#pragma unroll
                for (int kc = 0; kc < 2; ++kc) {
                    const halfx8 a = *(const halfx8*)&h2s[p][arow][kc * 32 + quad * 8];
#pragma unroll
                    for (int g = 0; g < 4; ++g)
                        acc2[g] = MFMA16H(a, wf[16 + g * 2 + kc], acc2[g]);
                }
                __builtin_amdgcn_s_setprio(0);
                // ---- L2 epilogue, in-register: 1 update per lane ----
                const int u = (wave - 8) * 16 + l15;
                const float iv = fast_sigmoid(acc2[0][0]);
                const float fv = fast_sigmoid(acc2[1][0]);
                const float gv = fast_tanh   (acc2[2][0]);
                const float ov = fast_sigmoid(acc2[3][0]);
                const float cn = fv * cst + iv * gv;
                cst = cn;
                const float h = ov * fast_tanh(cn);
                if (tt == T_SEQ) {
                    out[(size_t)(r0 + quad) * E2 + u] = h;
                } else {
                    h2s[pn][quad][u] = f2h(h);
                }
            }
            // ---- batched x staging, once every 8 steps ----
            if (stager && (tt & 7) == 0) {
#pragma unroll
                for (int j = 0; j < 8; ++j) {
                    const int t = tt + 8 + j;
                    if (t < T_SEQ) xs[t & 15][w2s][lane] = f2h(xr8[j]);
                }
#pragma unroll
                for (int j = 0; j < 8; ++j) {
                    const int t = tt + 16 + j;
                    if (t < T_SEQ) xr8[j] = xptr[(size_t)t * F_IN];
                }
            }
        }
        __syncthreads();   // single barrier: buf pn complete, buf p reads done
    }
}

extern "C" void kernel_launch(void* const* d_in, const int* in_sizes, int n_in,
                              void* d_out, int out_size, void* d_ws, size_t ws_size,
                              hipStream_t stream) {
    lstm_fused<<<128, 768, 0, stream>>>(
        (const float*)d_in[0], (const float*)d_in[1], (const float*)d_in[2],
        (const float*)d_in[3], (const float*)d_in[4], (const float*)d_in[5],
        (const float*)d_in[6], (const float*)d_in[7], (const float*)d_in[8],
        (float*)d_out);
}